// Round 4
// baseline (347.262 us; speedup 1.0000x reference)
//
#include <hip/hip_runtime.h>

// SMPL forward: B=512 batches, V=6890 verts, NB=10 shape dims, NJ=24 joints, 9 extra joints.
// Output fp32 (B, V+33, 3).

#define BATCH 512
#define NV 6890
#define NBD 10
#define NJ 24
#define NEXTRA 9
#define NOUT (NV + NJ + NEXTRA)   // 6923
#define VBLK ((NV + 255) / 256)   // 27 (lbs vertex blocks)
#define BPB 4                     // batches per block in LBS kernel
#define ECHUNK ((NV + 3) / 4)     // 1723 verts per extra-kernel block

__constant__ int c_par[NJ] = {-1,0,0,0,1,2,3,4,5,6,7,8,9,9,9,12,13,14,16,17,18,19,20,21};

// ---------------------------------------------------------------------------
// Kernel A: batch-independent regressor precompute.
// jtjs[j][0:3]      = sum_v Jreg[j,v] * v_template[v,k]
// jtjs[j][3+k*10+l] = sum_v Jreg[j,v] * shapedirs[v,k,l]
// grid NJ (=24 blocks), 256 threads, grid-stride over V, direct write
// (no atomics, no memset node needed).
// ---------------------------------------------------------------------------
__global__ __launch_bounds__(256) void precompute_kernel(
    const float* __restrict__ jreg,
    const float* __restrict__ smpl_t,
    const float* __restrict__ smil_t,
    const float* __restrict__ sdirs,
    const float* __restrict__ msc,
    float* __restrict__ jtjs)
{
    const int j = blockIdx.x;
    const float s = msc[0];

    float acc[33];
#pragma unroll
    for (int i = 0; i < 33; ++i) acc[i] = 0.f;

    for (int v = threadIdx.x; v < NV; v += 256) {
        const float w = jreg[j * NV + v];
#pragma unroll
        for (int k = 0; k < 3; ++k) {
            float vt = s * smpl_t[v * 3 + k] + (1.f - s) * smil_t[v * 3 + k];
            acc[k] = fmaf(w, vt, acc[k]);
        }
        const float2* sd2 = (const float2*)(sdirs + (size_t)v * 30);
#pragma unroll
        for (int i = 0; i < 15; ++i) {
            float2 x = sd2[i];
            acc[3 + 2 * i]     = fmaf(w, x.x, acc[3 + 2 * i]);
            acc[3 + 2 * i + 1] = fmaf(w, x.y, acc[3 + 2 * i + 1]);
        }
    }

    // butterfly reduce over 64-lane wave
#pragma unroll
    for (int i = 0; i < 33; ++i) {
        float x = acc[i];
        for (int off = 32; off; off >>= 1) x += __shfl_xor(x, off, 64);
        acc[i] = x;
    }

    __shared__ float red[4][33];
    const int lane = threadIdx.x & 63, wv = threadIdx.x >> 6;
    if (lane == 0) {
#pragma unroll
        for (int i = 0; i < 33; ++i) red[wv][i] = acc[i];
    }
    __syncthreads();
    if (threadIdx.x < 33) {
        jtjs[j * 33 + threadIdx.x] = red[0][threadIdx.x] + red[1][threadIdx.x]
                                   + red[2][threadIdx.x] + red[3][threadIdx.x];
    }
}

// ---------------------------------------------------------------------------
// Kernel B: per-batch joints — Rodrigues, kinematic chain, A matrices.
// grid BATCH, block 64 (one wave). Lanes 0..23 own joint j.
// Writes A[b,j] (3x4 row-major, 12 floats) to wsA and posed joints (+transl) to out.
// Also zero-inits the 27 extra-joint output floats for this batch (extra_kernel
// atomically accumulates into them later in stream order).
// ---------------------------------------------------------------------------
__global__ __launch_bounds__(64) void joints_kernel(
    const float* __restrict__ betas,
    const float* __restrict__ body_pose,
    const float* __restrict__ glob_or,
    const float* __restrict__ transl,
    const float* __restrict__ jtjs,
    float* __restrict__ wsA,
    float* __restrict__ out)
{
    const int b = blockIdx.x;
    const int j = threadIdx.x;

    __shared__ float sJ[NJ][3];     // J_shaped
    __shared__ float mats[NJ][12];  // [R | rel_t] 3x4 row-major
    __shared__ float chain[NJ][12];
    __shared__ float sbeta[NBD + 1];

    if (threadIdx.x < NBD + 1) sbeta[threadIdx.x] = betas[b * (NBD + 1) + threadIdx.x];

    // zero the extra-joint slots (threads 24..50, independent of joint work)
    if (threadIdx.x >= NJ && threadIdx.x < NJ + 3 * NEXTRA)
        out[((size_t)b * NOUT + NV + NJ) * 3 + (threadIdx.x - NJ)] = 0.f;

    __syncthreads();

    if (j < NJ) {
        const float beta0 = sbeta[0];
        // J_shaped[b,j,k]
#pragma unroll
        for (int k = 0; k < 3; ++k) {
            float a = jtjs[j * 33 + k];
#pragma unroll
            for (int l = 0; l < NBD; ++l) a = fmaf(sbeta[1 + l], jtjs[j * 33 + 3 + k * 10 + l], a);
            sJ[j][k] = a * beta0;
        }
        // Rodrigues. angle uses rvec+1e-8 per-component; axis uses raw rvec.
        float rx, ry, rz;
        if (j == 0) {
            rx = glob_or[b * 3 + 0]; ry = glob_or[b * 3 + 1]; rz = glob_or[b * 3 + 2];
        } else {
            rx = body_pose[b * 69 + (j - 1) * 3 + 0];
            ry = body_pose[b * 69 + (j - 1) * 3 + 1];
            rz = body_pose[b * 69 + (j - 1) * 3 + 2];
        }
        float ex = rx + 1e-8f, ey = ry + 1e-8f, ez = rz + 1e-8f;
        float ang = sqrtf(ex * ex + ey * ey + ez * ez);
        float inv = 1.f / ang;
        float ax = rx * inv, ay = ry * inv, az = rz * inv;
        float c = cosf(ang), s = sinf(ang), t = 1.f - c;
        // R = I + s*K + (1-c)*K^2
        mats[j][0]  = 1.f + t * (-(ay * ay + az * az));
        mats[j][1]  = -s * az + t * (ax * ay);
        mats[j][2]  =  s * ay + t * (ax * az);
        mats[j][4]  =  s * az + t * (ax * ay);
        mats[j][5]  = 1.f + t * (-(ax * ax + az * az));
        mats[j][6]  = -s * ax + t * (ay * az);
        mats[j][8]  = -s * ay + t * (ax * az);
        mats[j][9]  =  s * ax + t * (ay * az);
        mats[j][10] = 1.f + t * (-(ax * ax + ay * ay));
    }
    __syncthreads();
    if (j < NJ) {
        const int p = c_par[j];
        float t0 = sJ[j][0], t1 = sJ[j][1], t2 = sJ[j][2];
        if (p >= 0) { t0 -= sJ[p][0]; t1 -= sJ[p][1]; t2 -= sJ[p][2]; }
        mats[j][3] = t0; mats[j][7] = t1; mats[j][11] = t2;
    }
    __syncthreads();
    // serial chain compose on lane 0 (23 affine 3x4 compositions — trivial)
    if (threadIdx.x == 0) {
#pragma unroll
        for (int k = 0; k < 12; ++k) chain[0][k] = mats[0][k];
        for (int i = 1; i < NJ; ++i) {
            const int p = c_par[i];
#pragma unroll
            for (int r = 0; r < 3; ++r) {
#pragma unroll
                for (int col = 0; col < 4; ++col) {
                    float acc = (col == 3) ? chain[p][r * 4 + 3] : 0.f;
#pragma unroll
                    for (int q = 0; q < 3; ++q) acc = fmaf(chain[p][r * 4 + q], mats[i][q * 4 + col], acc);
                    chain[i][r * 4 + col] = acc;
                }
            }
        }
    }
    __syncthreads();
    if (j < NJ) {
        float A[12];
#pragma unroll
        for (int k = 0; k < 12; ++k) A[k] = chain[j][k];
        const float c0 = A[3], c1 = A[7], c2 = A[11];
        const float j0 = sJ[j][0], j1 = sJ[j][1], j2 = sJ[j][2];
        A[3]  = c0 - (A[0] * j0 + A[1] * j1 + A[2]  * j2);
        A[7]  = c1 - (A[4] * j0 + A[5] * j1 + A[6]  * j2);
        A[11] = c2 - (A[8] * j0 + A[9] * j1 + A[10] * j2);
#pragma unroll
        for (int k = 0; k < 12; ++k) wsA[((size_t)b * NJ + j) * 12 + k] = A[k];
        // posed joints + transl
        const float tx = transl[b * 3 + 0], ty = transl[b * 3 + 1], tz = transl[b * 3 + 2];
        const size_t o = ((size_t)b * NOUT + NV + j) * 3;
        out[o + 0] = c0 + tx; out[o + 1] = c1 + ty; out[o + 2] = c2 + tz;
    }
}

// ---------------------------------------------------------------------------
// Kernel C: LBS skinning — the dominant cost.
// grid (VBLK, BATCH/BPB), block 256; 1 vertex/thread, BPB=4 batches/block.
// v4: round-0 structure (no LDS, no mid-kernel barrier — round 3's barrier
// pinned 57 floats live → VGPR 136 → occupancy collapse; LDS broadcast reads
// deliver only 16B unique data per ~12 CU-cycles → LDS-pipe-bound).
// The one change vs round 0: A[b] is read via VECTOR global loads instead of
// s_load. An opaque v_mov_b32 zero mixed into the pointer defeats uniformity
// analysis, so the 72 float4 loads/batch go down the vector path: same-address
// lanes coalesce to one L1 request (A for the block = 4.6 KB, L1-resident),
// ~10 loads in flight with fine-grained vmcnt waits — removing the ~4 serial
// full lgkmcnt drains/batch that capped round 0 at VALUBusy 37%.
// launch_bounds(256,4): VGPR cap 128 → 4 waves/SIMD, room for load buffers.
// ---------------------------------------------------------------------------
__global__ __launch_bounds__(256, 4) void lbs_kernel(
    const float* __restrict__ betas,
    const float* __restrict__ transl,
    const float* __restrict__ msc,
    const float* __restrict__ smpl_t,
    const float* __restrict__ smil_t,
    const float* __restrict__ sdirs,
    const float* __restrict__ lbsw,
    const float* __restrict__ wsA,
    float* __restrict__ out)
{
    const int tid = threadIdx.x;
    const int b0 = blockIdx.y * BPB;
    const int v = blockIdx.x * 256 + tid;
    const bool valid = v < NV;
    const int vc = valid ? v : NV - 1;
    const float s = msc[0];

    // opaque zero in a VGPR — compiler cannot prove it is 0, so any address
    // containing it is treated as divergent → vector loads, not s_load.
    int vzero;
    asm("v_mov_b32 %0, 0" : "=v"(vzero));

    // per-vertex, batch-independent data (compiler free to keep or remat from
    // L2 per batch — round-0 behavior, proven cheap)
    float vt[3];
#pragma unroll
    for (int k = 0; k < 3; ++k)
        vt[k] = s * smpl_t[vc * 3 + k] + (1.f - s) * smil_t[vc * 3 + k];

    float sd[30];
    {
        const float2* sd2 = (const float2*)(sdirs + (size_t)vc * 30);
#pragma unroll
        for (int i = 0; i < 15; ++i) { float2 x = sd2[i]; sd[2 * i] = x.x; sd[2 * i + 1] = x.y; }
    }
    float w[NJ];
    {
        const float4* w4 = (const float4*)(lbsw + (size_t)vc * NJ);
#pragma unroll
        for (int i = 0; i < 6; ++i) {
            float4 x = w4[i];
            w[4 * i] = x.x; w[4 * i + 1] = x.y; w[4 * i + 2] = x.z; w[4 * i + 3] = x.w;
        }
    }

#pragma unroll
    for (int bb = 0; bb < BPB; ++bb) {
        const int b = b0 + bb;
        const float* __restrict__ Bb = betas + b * (NBD + 1);  // uniform → s_load (11 floats, cheap)
        // A via vector path: one address VGPR pair, 72 dwordx4 with imm offsets
        const float4* Ab4 = (const float4*)(wsA + (size_t)b * NJ * 12) + vzero;

        // v_shaped
        float vs[3];
#pragma unroll
        for (int k = 0; k < 3; ++k) {
            float a = vt[k];
#pragma unroll
            for (int l = 0; l < NBD; ++l) a = fmaf(Bb[1 + l], sd[k * 10 + l], a);
            vs[k] = a * Bb[0];
        }

        // T = sum_j w_j * A_j (3x4)
        float T[12];
#pragma unroll
        for (int k = 0; k < 12; ++k) T[k] = 0.f;
#pragma unroll
        for (int jj = 0; jj < NJ; ++jj) {
            const float ww = w[jj];
            const float4 a0 = Ab4[jj * 3 + 0];
            const float4 a1 = Ab4[jj * 3 + 1];
            const float4 a2 = Ab4[jj * 3 + 2];
            T[0]  = fmaf(ww, a0.x, T[0]);
            T[1]  = fmaf(ww, a0.y, T[1]);
            T[2]  = fmaf(ww, a0.z, T[2]);
            T[3]  = fmaf(ww, a0.w, T[3]);
            T[4]  = fmaf(ww, a1.x, T[4]);
            T[5]  = fmaf(ww, a1.y, T[5]);
            T[6]  = fmaf(ww, a1.z, T[6]);
            T[7]  = fmaf(ww, a1.w, T[7]);
            T[8]  = fmaf(ww, a2.x, T[8]);
            T[9]  = fmaf(ww, a2.y, T[9]);
            T[10] = fmaf(ww, a2.z, T[10]);
            T[11] = fmaf(ww, a2.w, T[11]);
        }

        if (valid) {
            const float tx = transl[b * 3 + 0], ty = transl[b * 3 + 1], tz = transl[b * 3 + 2];
            const size_t o = ((size_t)b * NOUT + v) * 3;
            out[o + 0] = fmaf(T[0], vs[0], fmaf(T[1], vs[1], fmaf(T[2],  vs[2], T[3])))  + tx;
            out[o + 1] = fmaf(T[4], vs[0], fmaf(T[5], vs[1], fmaf(T[6],  vs[2], T[7])))  + ty;
            out[o + 2] = fmaf(T[8], vs[0], fmaf(T[9], vs[1], fmaf(T[10], vs[2], T[11]))) + tz;
        }
    }
}

// ---------------------------------------------------------------------------
// Kernel D: extra joints = J_regressor_extra @ (verts + transl).
// Softmax rows sum to 1, so regressing translated verts directly gives extra+t.
// grid (4, BATCH) — 4 vertex chunks per batch; partials atomicAdd'ed into the
// zero-initialized slots written by joints_kernel.
// ---------------------------------------------------------------------------
__global__ __launch_bounds__(256) void extra_kernel(
    const float* __restrict__ jre,
    float* out)
{
    const int b = blockIdx.y;
    const int v0 = blockIdx.x * ECHUNK;
    int vend = v0 + ECHUNK; if (vend > NV) vend = NV;
    const float* vb = out + (size_t)b * NOUT * 3;

    float acc[27];
#pragma unroll
    for (int i = 0; i < 27; ++i) acc[i] = 0.f;

    for (int v = v0 + threadIdx.x; v < vend; v += 256) {
        const float x = vb[v * 3 + 0], y = vb[v * 3 + 1], z = vb[v * 3 + 2];
#pragma unroll
        for (int e = 0; e < NEXTRA; ++e) {
            const float we = jre[e * NV + v];
            acc[e * 3 + 0] = fmaf(we, x, acc[e * 3 + 0]);
            acc[e * 3 + 1] = fmaf(we, y, acc[e * 3 + 1]);
            acc[e * 3 + 2] = fmaf(we, z, acc[e * 3 + 2]);
        }
    }

#pragma unroll
    for (int i = 0; i < 27; ++i) {
        float x = acc[i];
        for (int off = 32; off; off >>= 1) x += __shfl_xor(x, off, 64);
        acc[i] = x;
    }
    __shared__ float red[4][27];
    const int lane = threadIdx.x & 63, wv = threadIdx.x >> 6;
    if (lane == 0) {
#pragma unroll
        for (int i = 0; i < 27; ++i) red[wv][i] = acc[i];
    }
    __syncthreads();
    if (threadIdx.x < 27) {
        const float sum = red[0][threadIdx.x] + red[1][threadIdx.x]
                        + red[2][threadIdx.x] + red[3][threadIdx.x];
        atomicAdd(&out[((size_t)b * NOUT + NV + NJ) * 3 + threadIdx.x], sum);
    }
}

// ---------------------------------------------------------------------------
extern "C" void kernel_launch(void* const* d_in, const int* in_sizes, int n_in,
                              void* d_out, int out_size, void* d_ws, size_t ws_size,
                              hipStream_t stream) {
    const float* betas     = (const float*)d_in[0];
    const float* body_pose = (const float*)d_in[1];
    const float* glob_or   = (const float*)d_in[2];
    const float* transl    = (const float*)d_in[3];
    const float* msc       = (const float*)d_in[4];
    const float* smpl_t    = (const float*)d_in[5];
    const float* smil_t    = (const float*)d_in[6];
    const float* sdirs     = (const float*)d_in[7];
    const float* jreg      = (const float*)d_in[8];
    const float* lbsw      = (const float*)d_in[9];
    const float* jre       = (const float*)d_in[10];
    // d_in[11] = parents (hard-coded in c_par)

    float* out  = (float*)d_out;
    float* ws   = (float*)d_ws;
    float* jtjs = ws;                 // NJ*33 = 792 floats
    float* wsA  = ws + 792;           // BATCH*NJ*12 = 147456 floats

    // precompute writes jtjs directly (no atomics) — no memset node needed
    precompute_kernel<<<NJ, 256, 0, stream>>>(jreg, smpl_t, smil_t, sdirs, msc, jtjs);

    joints_kernel<<<BATCH, 64, 0, stream>>>(betas, body_pose, glob_or, transl, jtjs, wsA, out);

    dim3 gC(VBLK, BATCH / BPB);
    lbs_kernel<<<gC, 256, 0, stream>>>(betas, transl, msc, smpl_t, smil_t, sdirs, lbsw, wsA, out);

    dim3 gE(4, BATCH);
    extra_kernel<<<gE, 256, 0, stream>>>(jre, out);
}

// Round 5
// 291.633 us; speedup vs baseline: 1.1907x; 1.1907x over previous
//
#include <hip/hip_runtime.h>

// SMPL forward: B=512 batches, V=6890 verts, NB=10 shape dims, NJ=24 joints, 9 extra joints.
// Output fp32 (B, V+33, 3).

#define BATCH 512
#define NV 6890
#define NBD 10
#define NJ 24
#define NEXTRA 9
#define NOUT (NV + NJ + NEXTRA)   // 6923
#define BPB 4                     // batches per block in LBS kernel
#define VPT 2                     // vertices per thread in LBS kernel
#define VSPAN (256 * VPT)         // 512 verts per block
#define NXB ((NV + VSPAN - 1) / VSPAN)  // 14
#define ECHUNK ((NV + 3) / 4)     // 1723 verts per extra-kernel block
#define PCHUNK 8                  // precompute V-chunks (partial sums)
#define PCLEN ((NV + PCHUNK - 1) / PCHUNK)  // 862

__constant__ int c_par[NJ] = {-1,0,0,0,1,2,3,4,5,6,7,8,9,9,9,12,13,14,16,17,18,19,20,21};
// kinematic depth of each joint (par of depth-k joint has depth k-1)
__constant__ int c_dep[NJ] = {0,1,1,1,2,2,2,3,3,3,4,4,4,4,4,5,5,5,6,6,7,7,8,8};

// ---------------------------------------------------------------------------
// Kernel A: batch-independent regressor precompute → PARTIALS (no atomics,
// no memset). grid (PCHUNK, NJ) = 192 blocks, block 256.
// jtjs_part[c][j][0:3]      = sum_{v in chunk c} Jreg[j,v] * v_template[v,k]
// jtjs_part[c][j][3+k*10+l] = sum_{v in chunk c} Jreg[j,v] * shapedirs[v,k,l]
// joints_kernel sums the PCHUNK partials.
// ---------------------------------------------------------------------------
__global__ __launch_bounds__(256) void precompute_kernel(
    const float* __restrict__ jreg,
    const float* __restrict__ smpl_t,
    const float* __restrict__ smil_t,
    const float* __restrict__ sdirs,
    const float* __restrict__ msc,
    float* __restrict__ jtjs_part)
{
    const int c = blockIdx.x;
    const int j = blockIdx.y;
    const float s = msc[0];

    const int vbeg = c * PCLEN;
    const int vend_ = (vbeg + PCLEN < NV) ? vbeg + PCLEN : NV;

    float acc[33];
#pragma unroll
    for (int i = 0; i < 33; ++i) acc[i] = 0.f;

    for (int v = vbeg + threadIdx.x; v < vend_; v += 256) {
        const float w = jreg[j * NV + v];
#pragma unroll
        for (int k = 0; k < 3; ++k) {
            float vt = s * smpl_t[v * 3 + k] + (1.f - s) * smil_t[v * 3 + k];
            acc[k] = fmaf(w, vt, acc[k]);
        }
        const float2* sd2 = (const float2*)(sdirs + (size_t)v * 30);
#pragma unroll
        for (int i = 0; i < 15; ++i) {
            float2 x = sd2[i];
            acc[3 + 2 * i]     = fmaf(w, x.x, acc[3 + 2 * i]);
            acc[3 + 2 * i + 1] = fmaf(w, x.y, acc[3 + 2 * i + 1]);
        }
    }

    // butterfly reduce over 64-lane wave
#pragma unroll
    for (int i = 0; i < 33; ++i) {
        float x = acc[i];
        for (int off = 32; off; off >>= 1) x += __shfl_xor(x, off, 64);
        acc[i] = x;
    }

    __shared__ float red[4][33];
    const int lane = threadIdx.x & 63, wv = threadIdx.x >> 6;
    if (lane == 0) {
#pragma unroll
        for (int i = 0; i < 33; ++i) red[wv][i] = acc[i];
    }
    __syncthreads();
    if (threadIdx.x < 33) {
        jtjs_part[(c * NJ + j) * 33 + threadIdx.x] =
            red[0][threadIdx.x] + red[1][threadIdx.x]
          + red[2][threadIdx.x] + red[3][threadIdx.x];
    }
}

// ---------------------------------------------------------------------------
// Kernel B: per-batch joints — Rodrigues, kinematic chain, A matrices.
// grid BATCH, block 64 (one wave). Lanes 0..23 own joint j.
// v5: sums the PCHUNK regressor partials (replacing the atomics/memset), and
// the chain composition is parallelized by kinematic DEPTH (8 levels, all
// lanes of a level compose concurrently) instead of serial on lane 0.
// ---------------------------------------------------------------------------
__global__ __launch_bounds__(64) void joints_kernel(
    const float* __restrict__ betas,
    const float* __restrict__ body_pose,
    const float* __restrict__ glob_or,
    const float* __restrict__ transl,
    const float* __restrict__ jtjs_part,
    float* __restrict__ wsA,
    float* __restrict__ out)
{
    const int b = blockIdx.x;
    const int j = threadIdx.x;

    __shared__ float sJ[NJ][3];     // J_shaped
    __shared__ float mats[NJ][12];  // [R | rel_t] 3x4 row-major
    __shared__ float chain[NJ][12];
    __shared__ float sbeta[NBD + 1];

    if (threadIdx.x < NBD + 1) sbeta[threadIdx.x] = betas[b * (NBD + 1) + threadIdx.x];

    // zero the extra-joint slots (threads 24..50, independent of joint work)
    if (threadIdx.x >= NJ && threadIdx.x < NJ + 3 * NEXTRA)
        out[((size_t)b * NOUT + NV + NJ) * 3 + (threadIdx.x - NJ)] = 0.f;

    __syncthreads();

    if (j < NJ) {
        // sum regressor partials for this joint
        float jt[33];
#pragma unroll
        for (int i = 0; i < 33; ++i) jt[i] = 0.f;
        for (int c = 0; c < PCHUNK; ++c) {
#pragma unroll
            for (int i = 0; i < 33; ++i) jt[i] += jtjs_part[(c * NJ + j) * 33 + i];
        }

        const float beta0 = sbeta[0];
        // J_shaped[b,j,k]
#pragma unroll
        for (int k = 0; k < 3; ++k) {
            float a = jt[k];
#pragma unroll
            for (int l = 0; l < NBD; ++l) a = fmaf(sbeta[1 + l], jt[3 + k * 10 + l], a);
            sJ[j][k] = a * beta0;
        }
        // Rodrigues. angle uses rvec+1e-8 per-component; axis uses raw rvec.
        float rx, ry, rz;
        if (j == 0) {
            rx = glob_or[b * 3 + 0]; ry = glob_or[b * 3 + 1]; rz = glob_or[b * 3 + 2];
        } else {
            rx = body_pose[b * 69 + (j - 1) * 3 + 0];
            ry = body_pose[b * 69 + (j - 1) * 3 + 1];
            rz = body_pose[b * 69 + (j - 1) * 3 + 2];
        }
        float ex = rx + 1e-8f, ey = ry + 1e-8f, ez = rz + 1e-8f;
        float ang = sqrtf(ex * ex + ey * ey + ez * ez);
        float inv = 1.f / ang;
        float ax = rx * inv, ay = ry * inv, az = rz * inv;
        float c = cosf(ang), s = sinf(ang), t = 1.f - c;
        // R = I + s*K + (1-c)*K^2
        mats[j][0]  = 1.f + t * (-(ay * ay + az * az));
        mats[j][1]  = -s * az + t * (ax * ay);
        mats[j][2]  =  s * ay + t * (ax * az);
        mats[j][4]  =  s * az + t * (ax * ay);
        mats[j][5]  = 1.f + t * (-(ax * ax + az * az));
        mats[j][6]  = -s * ax + t * (ay * az);
        mats[j][8]  = -s * ay + t * (ax * az);
        mats[j][9]  =  s * ax + t * (ay * az);
        mats[j][10] = 1.f + t * (-(ax * ax + ay * ay));
    }
    __syncthreads();
    if (j < NJ) {
        const int p = c_par[j];
        float t0 = sJ[j][0], t1 = sJ[j][1], t2 = sJ[j][2];
        if (p >= 0) { t0 -= sJ[p][0]; t1 -= sJ[p][1]; t2 -= sJ[p][2]; }
        mats[j][3] = t0; mats[j][7] = t1; mats[j][11] = t2;
    }
    __syncthreads();
    // chain compose, parallel over kinematic depth levels (max depth 8).
    // level-k joints depend only on level-(k-1) parents → barrier per level.
    if (j == 0) {
#pragma unroll
        for (int k = 0; k < 12; ++k) chain[0][k] = mats[0][k];
    }
    __syncthreads();
    for (int lev = 1; lev <= 8; ++lev) {
        if (j < NJ && c_dep[j] == lev) {
            const int p = c_par[j];
            float r_[12];
#pragma unroll
            for (int r = 0; r < 3; ++r) {
#pragma unroll
                for (int col = 0; col < 4; ++col) {
                    float acc = (col == 3) ? chain[p][r * 4 + 3] : 0.f;
#pragma unroll
                    for (int q = 0; q < 3; ++q) acc = fmaf(chain[p][r * 4 + q], mats[j][q * 4 + col], acc);
                    r_[r * 4 + col] = acc;
                }
            }
#pragma unroll
            for (int k = 0; k < 12; ++k) chain[j][k] = r_[k];
        }
        __syncthreads();
    }
    if (j < NJ) {
        float A[12];
#pragma unroll
        for (int k = 0; k < 12; ++k) A[k] = chain[j][k];
        const float c0 = A[3], c1 = A[7], c2 = A[11];
        const float j0 = sJ[j][0], j1 = sJ[j][1], j2 = sJ[j][2];
        A[3]  = c0 - (A[0] * j0 + A[1] * j1 + A[2]  * j2);
        A[7]  = c1 - (A[4] * j0 + A[5] * j1 + A[6]  * j2);
        A[11] = c2 - (A[8] * j0 + A[9] * j1 + A[10] * j2);
#pragma unroll
        for (int k = 0; k < 12; ++k) wsA[((size_t)b * NJ + j) * 12 + k] = A[k];
        // posed joints + transl
        const float tx = transl[b * 3 + 0], ty = transl[b * 3 + 1], tz = transl[b * 3 + 2];
        const size_t o = ((size_t)b * NOUT + NV + j) * 3;
        out[o + 0] = c0 + tx; out[o + 1] = c1 + ty; out[o + 2] = c2 + tz;
    }
}

// ---------------------------------------------------------------------------
// Kernel C: LBS skinning — the dominant cost.
// v5 = round-0 structure (scalar s_load A path — measured best of the three
// delivery pipes: s_load 54µs < LDS-broadcast 114µs < vector-flat 203µs),
// with exactly one change: VPT=2 vertices/thread so each scalar-drained
// A float feeds TWO v_fmacs instead of one. sd (shapedirs) is streamed
// in-loop, NOT register-cached: round 0's VGPR=44 proved the compiler
// remats these L2-hit loads anyway, and caching 60 floats is what spilled
// round 2. NO __launch_bounds__ min-waves arg (rounds 2 & 4 both spilled
// when the allocator was given a budget hint; plain (256) never spilled).
// Spill tripwire: WRITE_SIZE must stay ≈41.7 MB.
// ---------------------------------------------------------------------------
__global__ __launch_bounds__(256) void lbs_kernel(
    const float* __restrict__ betas,
    const float* __restrict__ transl,
    const float* __restrict__ msc,
    const float* __restrict__ smpl_t,
    const float* __restrict__ smil_t,
    const float* __restrict__ sdirs,
    const float* __restrict__ lbsw,
    const float* __restrict__ wsA,
    float* __restrict__ out)
{
    const int tid = threadIdx.x;
    const int b0 = blockIdx.y * BPB;
    const float s = msc[0];

    int  vv[VPT];
    bool val[VPT];
    int  vc[VPT];
#pragma unroll
    for (int p = 0; p < VPT; ++p) {
        vv[p]  = blockIdx.x * VSPAN + p * 256 + tid;
        val[p] = vv[p] < NV;
        vc[p]  = val[p] ? vv[p] : NV - 1;
    }

    // per-vertex batch-independent data; compiler free to cache or remat
    float vt[VPT][3], w[VPT][NJ];
#pragma unroll
    for (int p = 0; p < VPT; ++p) {
#pragma unroll
        for (int k = 0; k < 3; ++k)
            vt[p][k] = s * smpl_t[vc[p] * 3 + k] + (1.f - s) * smil_t[vc[p] * 3 + k];
        const float4* w4 = (const float4*)(lbsw + (size_t)vc[p] * NJ);
#pragma unroll
        for (int i = 0; i < 6; ++i) {
            float4 x = w4[i];
            w[p][4 * i]     = x.x; w[p][4 * i + 1] = x.y;
            w[p][4 * i + 2] = x.z; w[p][4 * i + 3] = x.w;
        }
    }

#pragma unroll
    for (int bb = 0; bb < BPB; ++bb) {
        const int b = b0 + bb;
        const float* __restrict__ Bb = betas + b * (NBD + 1);     // uniform → s_load
        const float* __restrict__ Ab = wsA + (size_t)b * NJ * 12; // uniform → s_load

        // v_shaped; sd streamed from L1/L2 (float2, same accumulation order
        // as reference: l ascending)
        float vs[VPT][3];
#pragma unroll
        for (int p = 0; p < VPT; ++p) {
            const float2* sd2 = (const float2*)(sdirs + (size_t)vc[p] * 30);
#pragma unroll
            for (int k = 0; k < 3; ++k) {
                float a = vt[p][k];
#pragma unroll
                for (int h = 0; h < 5; ++h) {
                    float2 x = sd2[k * 5 + h];
                    a = fmaf(Bb[1 + 2 * h],     x.x, a);
                    a = fmaf(Bb[1 + 2 * h + 1], x.y, a);
                }
                vs[p][k] = a * Bb[0];
            }
        }

        // T = sum_j w_j * A_j (3x4); A uniform → scalar operand of v_fmac;
        // each A float feeds VPT fmacs.
        float T[VPT][12];
#pragma unroll
        for (int p = 0; p < VPT; ++p)
#pragma unroll
            for (int k = 0; k < 12; ++k) T[p][k] = 0.f;

#pragma unroll
        for (int jj = 0; jj < NJ; ++jj) {
#pragma unroll
            for (int k = 0; k < 12; ++k) {
                const float a = Ab[jj * 12 + k];
#pragma unroll
                for (int p = 0; p < VPT; ++p)
                    T[p][k] = fmaf(w[p][jj], a, T[p][k]);
            }
        }

        const float tx = transl[b * 3 + 0], ty = transl[b * 3 + 1], tz = transl[b * 3 + 2];
#pragma unroll
        for (int p = 0; p < VPT; ++p) {
            if (val[p]) {
                const size_t o = ((size_t)b * NOUT + vv[p]) * 3;
                out[o + 0] = fmaf(T[p][0], vs[p][0], fmaf(T[p][1], vs[p][1], fmaf(T[p][2],  vs[p][2],  T[p][3])))  + tx;
                out[o + 1] = fmaf(T[p][4], vs[p][0], fmaf(T[p][5], vs[p][1], fmaf(T[p][6],  vs[p][2],  T[p][7])))  + ty;
                out[o + 2] = fmaf(T[p][8], vs[p][0], fmaf(T[p][9], vs[p][1], fmaf(T[p][10], vs[p][2],  T[p][11]))) + tz;
            }
        }
    }
}

// ---------------------------------------------------------------------------
// Kernel D: extra joints = J_regressor_extra @ (verts + transl).
// Softmax rows sum to 1, so regressing translated verts directly gives extra+t.
// grid (4, BATCH); partials atomicAdd'ed into slots zeroed by joints_kernel.
// ---------------------------------------------------------------------------
__global__ __launch_bounds__(256) void extra_kernel(
    const float* __restrict__ jre,
    float* out)
{
    const int b = blockIdx.y;
    const int v0 = blockIdx.x * ECHUNK;
    int vend = v0 + ECHUNK; if (vend > NV) vend = NV;
    const float* vb = out + (size_t)b * NOUT * 3;

    float acc[27];
#pragma unroll
    for (int i = 0; i < 27; ++i) acc[i] = 0.f;

    for (int v = v0 + threadIdx.x; v < vend; v += 256) {
        const float x = vb[v * 3 + 0], y = vb[v * 3 + 1], z = vb[v * 3 + 2];
#pragma unroll
        for (int e = 0; e < NEXTRA; ++e) {
            const float we = jre[e * NV + v];
            acc[e * 3 + 0] = fmaf(we, x, acc[e * 3 + 0]);
            acc[e * 3 + 1] = fmaf(we, y, acc[e * 3 + 1]);
            acc[e * 3 + 2] = fmaf(we, z, acc[e * 3 + 2]);
        }
    }

#pragma unroll
    for (int i = 0; i < 27; ++i) {
        float x = acc[i];
        for (int off = 32; off; off >>= 1) x += __shfl_xor(x, off, 64);
        acc[i] = x;
    }
    __shared__ float red[4][27];
    const int lane = threadIdx.x & 63, wv = threadIdx.x >> 6;
    if (lane == 0) {
#pragma unroll
        for (int i = 0; i < 27; ++i) red[wv][i] = acc[i];
    }
    __syncthreads();
    if (threadIdx.x < 27) {
        const float sum = red[0][threadIdx.x] + red[1][threadIdx.x]
                        + red[2][threadIdx.x] + red[3][threadIdx.x];
        atomicAdd(&out[((size_t)b * NOUT + NV + NJ) * 3 + threadIdx.x], sum);
    }
}

// ---------------------------------------------------------------------------
extern "C" void kernel_launch(void* const* d_in, const int* in_sizes, int n_in,
                              void* d_out, int out_size, void* d_ws, size_t ws_size,
                              hipStream_t stream) {
    const float* betas     = (const float*)d_in[0];
    const float* body_pose = (const float*)d_in[1];
    const float* glob_or   = (const float*)d_in[2];
    const float* transl    = (const float*)d_in[3];
    const float* msc       = (const float*)d_in[4];
    const float* smpl_t    = (const float*)d_in[5];
    const float* smil_t    = (const float*)d_in[6];
    const float* sdirs     = (const float*)d_in[7];
    const float* jreg      = (const float*)d_in[8];
    const float* lbsw      = (const float*)d_in[9];
    const float* jre       = (const float*)d_in[10];
    // d_in[11] = parents (hard-coded in c_par)

    float* out  = (float*)d_out;
    float* ws   = (float*)d_ws;
    float* wsA       = ws;                         // BATCH*NJ*12 = 147456 floats
    float* jtjs_part = ws + (size_t)BATCH * NJ * 12; // PCHUNK*NJ*33 = 6336 floats

    dim3 gA(PCHUNK, NJ);
    precompute_kernel<<<gA, 256, 0, stream>>>(jreg, smpl_t, smil_t, sdirs, msc, jtjs_part);

    joints_kernel<<<BATCH, 64, 0, stream>>>(betas, body_pose, glob_or, transl, jtjs_part, wsA, out);

    dim3 gC(NXB, BATCH / BPB);
    lbs_kernel<<<gC, 256, 0, stream>>>(betas, transl, msc, smpl_t, smil_t, sdirs, lbsw, wsA, out);

    dim3 gE(4, BATCH);
    extra_kernel<<<gE, 256, 0, stream>>>(jre, out);
}

// Round 6
// 175.330 us; speedup vs baseline: 1.9806x; 1.6633x over previous
//
#include <hip/hip_runtime.h>

// SMPL forward: B=512 batches, V=6890 verts, NB=10 shape dims, NJ=24 joints, 9 extra joints.
// Output fp32 (B, V+33, 3).
//
// Round-6 consolidation: lbs_kernel is the ROUND-0 version verbatim (54 µs
// measured; all four structural variants regressed: LDS=114, VPT2-stream=173,
// VPT2-pin=178, vector=203). Small kernels are the round-5 measured-best
// stack (residue 117.7 µs vs 133.4 in round 0).

#define BATCH 512
#define NV 6890
#define NBD 10
#define NJ 24
#define NEXTRA 9
#define NOUT (NV + NJ + NEXTRA)   // 6923
#define VBLK ((NV + 255) / 256)   // 27
#define BPB 4                     // batches per block in LBS kernel
#define ECHUNK ((NV + 3) / 4)     // 1723 verts per extra-kernel block
#define PCHUNK 8                  // precompute V-chunks (partial sums)
#define PCLEN ((NV + PCHUNK - 1) / PCHUNK)  // 862

__constant__ int c_par[NJ] = {-1,0,0,0,1,2,3,4,5,6,7,8,9,9,9,12,13,14,16,17,18,19,20,21};
// kinematic depth of each joint (parent of depth-k joint has depth k-1)
__constant__ int c_dep[NJ] = {0,1,1,1,2,2,2,3,3,3,4,4,4,4,4,5,5,5,6,6,7,7,8,8};

// ---------------------------------------------------------------------------
// Kernel A: batch-independent regressor precompute → PARTIALS (no atomics,
// no memset). grid (PCHUNK, NJ) = 192 blocks, block 256.
// jtjs_part[c][j][0:3]      = sum_{v in chunk c} Jreg[j,v] * v_template[v,k]
// jtjs_part[c][j][3+k*10+l] = sum_{v in chunk c} Jreg[j,v] * shapedirs[v,k,l]
// joints_kernel sums the PCHUNK partials. (Measured best: 192-block partials
// beat both the 648-block atomic version and the 24-block direct version.)
// ---------------------------------------------------------------------------
__global__ __launch_bounds__(256) void precompute_kernel(
    const float* __restrict__ jreg,
    const float* __restrict__ smpl_t,
    const float* __restrict__ smil_t,
    const float* __restrict__ sdirs,
    const float* __restrict__ msc,
    float* __restrict__ jtjs_part)
{
    const int c = blockIdx.x;
    const int j = blockIdx.y;
    const float s = msc[0];

    const int vbeg = c * PCLEN;
    const int vend_ = (vbeg + PCLEN < NV) ? vbeg + PCLEN : NV;

    float acc[33];
#pragma unroll
    for (int i = 0; i < 33; ++i) acc[i] = 0.f;

    for (int v = vbeg + threadIdx.x; v < vend_; v += 256) {
        const float w = jreg[j * NV + v];
#pragma unroll
        for (int k = 0; k < 3; ++k) {
            float vt = s * smpl_t[v * 3 + k] + (1.f - s) * smil_t[v * 3 + k];
            acc[k] = fmaf(w, vt, acc[k]);
        }
        const float2* sd2 = (const float2*)(sdirs + (size_t)v * 30);
#pragma unroll
        for (int i = 0; i < 15; ++i) {
            float2 x = sd2[i];
            acc[3 + 2 * i]     = fmaf(w, x.x, acc[3 + 2 * i]);
            acc[3 + 2 * i + 1] = fmaf(w, x.y, acc[3 + 2 * i + 1]);
        }
    }

    // butterfly reduce over 64-lane wave
#pragma unroll
    for (int i = 0; i < 33; ++i) {
        float x = acc[i];
        for (int off = 32; off; off >>= 1) x += __shfl_xor(x, off, 64);
        acc[i] = x;
    }

    __shared__ float red[4][33];
    const int lane = threadIdx.x & 63, wv = threadIdx.x >> 6;
    if (lane == 0) {
#pragma unroll
        for (int i = 0; i < 33; ++i) red[wv][i] = acc[i];
    }
    __syncthreads();
    if (threadIdx.x < 33) {
        jtjs_part[(c * NJ + j) * 33 + threadIdx.x] =
            red[0][threadIdx.x] + red[1][threadIdx.x]
          + red[2][threadIdx.x] + red[3][threadIdx.x];
    }
}

// ---------------------------------------------------------------------------
// Kernel B: per-batch joints — Rodrigues, kinematic chain, A matrices.
// grid BATCH, block 64 (one wave). Lanes 0..23 own joint j.
// Sums the PCHUNK regressor partials; chain composition parallelized by
// kinematic depth (8 levels). Zero-inits the 27 extra-joint output floats.
// ---------------------------------------------------------------------------
__global__ __launch_bounds__(64) void joints_kernel(
    const float* __restrict__ betas,
    const float* __restrict__ body_pose,
    const float* __restrict__ glob_or,
    const float* __restrict__ transl,
    const float* __restrict__ jtjs_part,
    float* __restrict__ wsA,
    float* __restrict__ out)
{
    const int b = blockIdx.x;
    const int j = threadIdx.x;

    __shared__ float sJ[NJ][3];     // J_shaped
    __shared__ float mats[NJ][12];  // [R | rel_t] 3x4 row-major
    __shared__ float chain[NJ][12];
    __shared__ float sbeta[NBD + 1];

    if (threadIdx.x < NBD + 1) sbeta[threadIdx.x] = betas[b * (NBD + 1) + threadIdx.x];

    // zero the extra-joint slots (threads 24..50, independent of joint work)
    if (threadIdx.x >= NJ && threadIdx.x < NJ + 3 * NEXTRA)
        out[((size_t)b * NOUT + NV + NJ) * 3 + (threadIdx.x - NJ)] = 0.f;

    __syncthreads();

    if (j < NJ) {
        // sum regressor partials for this joint
        float jt[33];
#pragma unroll
        for (int i = 0; i < 33; ++i) jt[i] = 0.f;
        for (int c = 0; c < PCHUNK; ++c) {
#pragma unroll
            for (int i = 0; i < 33; ++i) jt[i] += jtjs_part[(c * NJ + j) * 33 + i];
        }

        const float beta0 = sbeta[0];
        // J_shaped[b,j,k]
#pragma unroll
        for (int k = 0; k < 3; ++k) {
            float a = jt[k];
#pragma unroll
            for (int l = 0; l < NBD; ++l) a = fmaf(sbeta[1 + l], jt[3 + k * 10 + l], a);
            sJ[j][k] = a * beta0;
        }
        // Rodrigues. angle uses rvec+1e-8 per-component; axis uses raw rvec.
        float rx, ry, rz;
        if (j == 0) {
            rx = glob_or[b * 3 + 0]; ry = glob_or[b * 3 + 1]; rz = glob_or[b * 3 + 2];
        } else {
            rx = body_pose[b * 69 + (j - 1) * 3 + 0];
            ry = body_pose[b * 69 + (j - 1) * 3 + 1];
            rz = body_pose[b * 69 + (j - 1) * 3 + 2];
        }
        float ex = rx + 1e-8f, ey = ry + 1e-8f, ez = rz + 1e-8f;
        float ang = sqrtf(ex * ex + ey * ey + ez * ez);
        float inv = 1.f / ang;
        float ax = rx * inv, ay = ry * inv, az = rz * inv;
        float c = cosf(ang), s = sinf(ang), t = 1.f - c;
        // R = I + s*K + (1-c)*K^2
        mats[j][0]  = 1.f + t * (-(ay * ay + az * az));
        mats[j][1]  = -s * az + t * (ax * ay);
        mats[j][2]  =  s * ay + t * (ax * az);
        mats[j][4]  =  s * az + t * (ax * ay);
        mats[j][5]  = 1.f + t * (-(ax * ax + az * az));
        mats[j][6]  = -s * ax + t * (ay * az);
        mats[j][8]  = -s * ay + t * (ax * az);
        mats[j][9]  =  s * ax + t * (ay * az);
        mats[j][10] = 1.f + t * (-(ax * ax + ay * ay));
    }
    __syncthreads();
    if (j < NJ) {
        const int p = c_par[j];
        float t0 = sJ[j][0], t1 = sJ[j][1], t2 = sJ[j][2];
        if (p >= 0) { t0 -= sJ[p][0]; t1 -= sJ[p][1]; t2 -= sJ[p][2]; }
        mats[j][3] = t0; mats[j][7] = t1; mats[j][11] = t2;
    }
    __syncthreads();
    // chain compose, parallel over kinematic depth levels (max depth 8).
    if (j == 0) {
#pragma unroll
        for (int k = 0; k < 12; ++k) chain[0][k] = mats[0][k];
    }
    __syncthreads();
    for (int lev = 1; lev <= 8; ++lev) {
        if (j < NJ && c_dep[j] == lev) {
            const int p = c_par[j];
            float r_[12];
#pragma unroll
            for (int r = 0; r < 3; ++r) {
#pragma unroll
                for (int col = 0; col < 4; ++col) {
                    float acc = (col == 3) ? chain[p][r * 4 + 3] : 0.f;
#pragma unroll
                    for (int q = 0; q < 3; ++q) acc = fmaf(chain[p][r * 4 + q], mats[j][q * 4 + col], acc);
                    r_[r * 4 + col] = acc;
                }
            }
#pragma unroll
            for (int k = 0; k < 12; ++k) chain[j][k] = r_[k];
        }
        __syncthreads();
    }
    if (j < NJ) {
        float A[12];
#pragma unroll
        for (int k = 0; k < 12; ++k) A[k] = chain[j][k];
        const float c0 = A[3], c1 = A[7], c2 = A[11];
        const float j0 = sJ[j][0], j1 = sJ[j][1], j2 = sJ[j][2];
        A[3]  = c0 - (A[0] * j0 + A[1] * j1 + A[2]  * j2);
        A[7]  = c1 - (A[4] * j0 + A[5] * j1 + A[6]  * j2);
        A[11] = c2 - (A[8] * j0 + A[9] * j1 + A[10] * j2);
#pragma unroll
        for (int k = 0; k < 12; ++k) wsA[((size_t)b * NJ + j) * 12 + k] = A[k];
        // posed joints + transl
        const float tx = transl[b * 3 + 0], ty = transl[b * 3 + 1], tz = transl[b * 3 + 2];
        const size_t o = ((size_t)b * NOUT + NV + j) * 3;
        out[o + 0] = c0 + tx; out[o + 1] = c1 + ty; out[o + 2] = c2 + tz;
    }
}

// ---------------------------------------------------------------------------
// Kernel C: LBS skinning — ROUND-0 VERSION VERBATIM (measured 54 µs, VGPR 44,
// VALUBusy 37%). A[b] is block-uniform → scalar s_load path; per-vertex data
// in registers with compiler free to rematerialize (VGPR stays at 44).
// Measured alternatives all regressed: LDS-broadcast 114 µs (LDS pipe:
// 16B/12cy), VPT=2 pinned 178 µs (spill), vector-flat 203 µs (spill),
// VPT=2 streamed 173 µs (SGPR pressure pushed A onto flat loads, 7x VALU
// inflation). Do not perturb without a counter-backed theory that addresses
// the scalar-path K$-miss drain directly.
// ---------------------------------------------------------------------------
__global__ __launch_bounds__(256) void lbs_kernel(
    const float* __restrict__ betas,
    const float* __restrict__ transl,
    const float* __restrict__ msc,
    const float* __restrict__ smpl_t,
    const float* __restrict__ smil_t,
    const float* __restrict__ sdirs,
    const float* __restrict__ lbsw,
    const float* __restrict__ wsA,
    float* __restrict__ out)
{
    const int v = blockIdx.x * 256 + threadIdx.x;
    const bool valid = v < NV;
    const int vc = valid ? v : NV - 1;
    const int b0 = blockIdx.y * BPB;
    const float s = msc[0];

    // per-vertex, batch-independent data → registers
    float vt[3];
#pragma unroll
    for (int k = 0; k < 3; ++k)
        vt[k] = s * smpl_t[vc * 3 + k] + (1.f - s) * smil_t[vc * 3 + k];

    float sd[30];
    {
        const float2* sd2 = (const float2*)(sdirs + (size_t)vc * 30);
#pragma unroll
        for (int i = 0; i < 15; ++i) { float2 x = sd2[i]; sd[2 * i] = x.x; sd[2 * i + 1] = x.y; }
    }
    float w[NJ];
    {
        const float4* w4 = (const float4*)(lbsw + (size_t)vc * NJ);
#pragma unroll
        for (int i = 0; i < 6; ++i) {
            float4 x = w4[i];
            w[4 * i] = x.x; w[4 * i + 1] = x.y; w[4 * i + 2] = x.z; w[4 * i + 3] = x.w;
        }
    }

#pragma unroll
    for (int bb = 0; bb < BPB; ++bb) {
        const int b = b0 + bb;
        const float* __restrict__ Bb = betas + b * (NBD + 1);   // uniform
        const float* __restrict__ Ab = wsA + (size_t)b * NJ * 12; // uniform

        // v_shaped
        float vs[3];
#pragma unroll
        for (int k = 0; k < 3; ++k) {
            float a = vt[k];
#pragma unroll
            for (int l = 0; l < NBD; ++l) a = fmaf(Bb[1 + l], sd[k * 10 + l], a);
            vs[k] = a * Bb[0];
        }

        // T = sum_j w_j * A_j (3x4), A uniform → scalar operand in v_fmac
        float T[12];
#pragma unroll
        for (int k = 0; k < 12; ++k) T[k] = 0.f;
#pragma unroll 4
        for (int jj = 0; jj < NJ; ++jj) {
            const float ww = w[jj];
#pragma unroll
            for (int k = 0; k < 12; ++k) T[k] = fmaf(ww, Ab[jj * 12 + k], T[k]);
        }

        if (valid) {
            const float tx = transl[b * 3 + 0], ty = transl[b * 3 + 1], tz = transl[b * 3 + 2];
            const size_t o = ((size_t)b * NOUT + v) * 3;
            out[o + 0] = fmaf(T[0], vs[0], fmaf(T[1], vs[1], fmaf(T[2],  vs[2], T[3])))  + tx;
            out[o + 1] = fmaf(T[4], vs[0], fmaf(T[5], vs[1], fmaf(T[6],  vs[2], T[7])))  + ty;
            out[o + 2] = fmaf(T[8], vs[0], fmaf(T[9], vs[1], fmaf(T[10], vs[2], T[11]))) + tz;
        }
    }
}

// ---------------------------------------------------------------------------
// Kernel D: extra joints = J_regressor_extra @ (verts + transl).
// Softmax rows sum to 1, so regressing translated verts directly gives extra+t.
// grid (4, BATCH); partials atomicAdd'ed into slots zeroed by joints_kernel.
// ---------------------------------------------------------------------------
__global__ __launch_bounds__(256) void extra_kernel(
    const float* __restrict__ jre,
    float* out)
{
    const int b = blockIdx.y;
    const int v0 = blockIdx.x * ECHUNK;
    int vend = v0 + ECHUNK; if (vend > NV) vend = NV;
    const float* vb = out + (size_t)b * NOUT * 3;

    float acc[27];
#pragma unroll
    for (int i = 0; i < 27; ++i) acc[i] = 0.f;

    for (int v = v0 + threadIdx.x; v < vend; v += 256) {
        const float x = vb[v * 3 + 0], y = vb[v * 3 + 1], z = vb[v * 3 + 2];
#pragma unroll
        for (int e = 0; e < NEXTRA; ++e) {
            const float we = jre[e * NV + v];
            acc[e * 3 + 0] = fmaf(we, x, acc[e * 3 + 0]);
            acc[e * 3 + 1] = fmaf(we, y, acc[e * 3 + 1]);
            acc[e * 3 + 2] = fmaf(we, z, acc[e * 3 + 2]);
        }
    }

#pragma unroll
    for (int i = 0; i < 27; ++i) {
        float x = acc[i];
        for (int off = 32; off; off >>= 1) x += __shfl_xor(x, off, 64);
        acc[i] = x;
    }
    __shared__ float red[4][27];
    const int lane = threadIdx.x & 63, wv = threadIdx.x >> 6;
    if (lane == 0) {
#pragma unroll
        for (int i = 0; i < 27; ++i) red[wv][i] = acc[i];
    }
    __syncthreads();
    if (threadIdx.x < 27) {
        const float sum = red[0][threadIdx.x] + red[1][threadIdx.x]
                        + red[2][threadIdx.x] + red[3][threadIdx.x];
        atomicAdd(&out[((size_t)b * NOUT + NV + NJ) * 3 + threadIdx.x], sum);
    }
}

// ---------------------------------------------------------------------------
extern "C" void kernel_launch(void* const* d_in, const int* in_sizes, int n_in,
                              void* d_out, int out_size, void* d_ws, size_t ws_size,
                              hipStream_t stream) {
    const float* betas     = (const float*)d_in[0];
    const float* body_pose = (const float*)d_in[1];
    const float* glob_or   = (const float*)d_in[2];
    const float* transl    = (const float*)d_in[3];
    const float* msc       = (const float*)d_in[4];
    const float* smpl_t    = (const float*)d_in[5];
    const float* smil_t    = (const float*)d_in[6];
    const float* sdirs     = (const float*)d_in[7];
    const float* jreg      = (const float*)d_in[8];
    const float* lbsw      = (const float*)d_in[9];
    const float* jre       = (const float*)d_in[10];
    // d_in[11] = parents (hard-coded in c_par)

    float* out  = (float*)d_out;
    float* ws   = (float*)d_ws;
    float* wsA       = ws;                           // BATCH*NJ*12 = 147456 floats
    float* jtjs_part = ws + (size_t)BATCH * NJ * 12; // PCHUNK*NJ*33 = 6336 floats

    dim3 gA(PCHUNK, NJ);
    precompute_kernel<<<gA, 256, 0, stream>>>(jreg, smpl_t, smil_t, sdirs, msc, jtjs_part);

    joints_kernel<<<BATCH, 64, 0, stream>>>(betas, body_pose, glob_or, transl, jtjs_part, wsA, out);

    dim3 gC(VBLK, BATCH / BPB);
    lbs_kernel<<<gC, 256, 0, stream>>>(betas, transl, msc, smpl_t, smil_t, sdirs, lbsw, wsA, out);

    dim3 gE(4, BATCH);
    extra_kernel<<<gE, 256, 0, stream>>>(jre, out);
}